// Round 10
// baseline (176.270 us; speedup 1.0000x reference)
//
#include <hip/hip_runtime.h>
#include <math.h>

#define H_IMG 1024
#define W_IMG 1280
#define NPIX (H_IMG * W_IMG)
#define RBLOCKS 256               // 1 block/CU, XCD-swizzled
#define RTPB 512                  // 8 waves/CU = 2 waves/SIMD (TLP retest under good mapping)
#define NWAVES (RTPB / 64)        // 8
#define STRIDE (RBLOCKS * RTPB)   // 131072 threads total
#define PPT (NPIX / STRIDE)       // 10 pixels per thread, exact
#define GSLOTS 5                  // slots per group
#define NGROUPS (PPT / GSLOTS)    // 2 groups
#define NACC 28                   // 21 JtJ upper-tri + 6 JtR + 1 count
#define NORM_THR 0.93969262f      // float(cos(20 deg))
#define DIST_THR2 0.04f           // 0.2^2
#define DAMPING 1e-6

// ws layout: [0..15] pose (f64); [16 .. 16+PART_DOUBLES) per-block partials;
// then one unsigned counter. (<60 KB total.)
#define PART_DOUBLES (RBLOCKS * NACC)

// ---------------------------------------------------------------------------
// Tiny init: only the completion counter needs a defined start value.
__global__ void icp_init0(double* __restrict__ ws) {
    if (threadIdx.x == 0) *(unsigned*)(ws + 16 + PART_DOUBLES) = 0u;
}

// ---------------------------------------------------------------------------
// 6x6 damped solve + exp_se3 + pose update, single thread, f64.
// it==0 chains off pose_in (float); else off pose_ws (f64).
__device__ void solve_and_update(const double* tot, double* pose_ws,
                                 const float* pose_in, int it,
                                 float* out, int write_out) {
    double JtJ[6][6];
    {
        int k = 0;
        for (int i = 0; i < 6; ++i)
            for (int j = i; j < 6; ++j) { JtJ[i][j] = tot[k]; JtJ[j][i] = tot[k]; ++k; }
    }
    double tr = 0.0;
    for (int i = 0; i < 6; ++i) tr += JtJ[i][i];

    double A[6][7];
    for (int i = 0; i < 6; ++i) {
        for (int j = 0; j < 6; ++j) A[i][j] = JtJ[i][j] + (i == j ? tr * DAMPING : 0.0);
        A[i][6] = -tot[21 + i];
    }
    for (int c = 0; c < 6; ++c) {
        int piv = c; double mx = fabs(A[c][c]);
        for (int r = c + 1; r < 6; ++r) {
            double ar = fabs(A[r][c]);
            if (ar > mx) { mx = ar; piv = r; }
        }
        if (piv != c) for (int j = 0; j < 7; ++j) { double tmp = A[c][j]; A[c][j] = A[piv][j]; A[piv][j] = tmp; }
        double d = A[c][c]; if (d == 0.0) d = 1e-30;
        for (int r = c + 1; r < 6; ++r) {
            double f = A[r][c] / d;
            for (int j = c; j < 7; ++j) A[r][j] -= f * A[c][j];
        }
    }
    double xi[6];
    for (int i = 5; i >= 0; --i) {
        double s = A[i][6];
        for (int j = i + 1; j < 6; ++j) s -= A[i][j] * xi[j];
        double d = A[i][i]; if (d == 0.0) d = 1e-30;
        xi[i] = s / d;
    }

    const double w0 = xi[0], w1 = xi[1], w2 = xi[2];
    const double v0 = xi[3], v1 = xi[4], v2 = xi[5];
    double wh[3][3] = { {0.0, -w2, w1}, {w2, 0.0, -w0}, {-w1, w0, 0.0} };
    double wh2[3][3];
    for (int i = 0; i < 3; ++i)
        for (int j = 0; j < 3; ++j) {
            double s = 0.0;
            for (int k = 0; k < 3; ++k) s += wh[i][k] * wh[k][j];
            wh2[i][j] = s;
        }
    const double theta = sqrt(w0 * w0 + w1 * w1 + w2 * w2);
    const double eps = 1e-8;
    const double ts = (theta > eps) ? theta : eps;
    const double st = sin(ts), ct = cos(ts);
    const double cA = st / ts;
    const double cB = (1.0 - ct) / (ts * ts);
    const double cC = (ts - st) / (ts * ts * ts);
    const bool small = (theta <= eps);

    double ew[3][3], Jm[3][3];
    for (int i = 0; i < 3; ++i)
        for (int j = 0; j < 3; ++j) {
            double eye = (i == j) ? 1.0 : 0.0;
            ew[i][j] = small ? eye : (eye + cA * wh[i][j] + cB * wh2[i][j]);
            Jm[i][j] = small ? eye : (eye + cB * wh[i][j] + cC * wh2[i][j]);
        }
    double Jv[3];
    for (int i = 0; i < 3; ++i) Jv[i] = Jm[i][0] * v0 + Jm[i][1] * v1 + Jm[i][2] * v2;

    double T[16] = { ew[0][0], ew[0][1], ew[0][2], Jv[0],
                     ew[1][0], ew[1][1], ew[1][2], Jv[1],
                     ew[2][0], ew[2][1], ew[2][2], Jv[2],
                     0.0, 0.0, 0.0, 1.0 };
    double P[16];
    for (int i = 0; i < 16; ++i) P[i] = (it == 0) ? (double)pose_in[i] : pose_ws[i];
    double NP[16];
    for (int i = 0; i < 4; ++i)
        for (int j = 0; j < 4; ++j) {
            double s = 0.0;
            for (int k = 0; k < 4; ++k) s += T[i * 4 + k] * P[k * 4 + j];
            NP[i * 4 + j] = s;
        }
    for (int i = 0; i < 16; ++i) pose_ws[i] = NP[i];

    if (write_out) {
        for (int i = 0; i < 16; ++i) out[i] = (float)NP[i];
        out[16] = (float)(tot[27] / (double)NPIX);
    }
}

// ---------------------------------------------------------------------------
// Shared epilogue: wave reduce -> per-block partial -> amLast reduce+solve.
__device__ __forceinline__ void reduce_and_finish(
    float a[NACC], double* ws, const float* pose_in, int it,
    float* out, int write_out)
{
    double* part = ws + 16;
    unsigned* counter = (unsigned*)(ws + 16 + PART_DOUBLES);

#pragma unroll
    for (int k = 0; k < NACC; ++k) {
        float val = a[k];
        for (int off = 32; off > 0; off >>= 1) val += __shfl_down(val, off, 64);
        a[k] = val;
    }

    __shared__ float sh[NWAVES][NACC];
    const int lane = threadIdx.x & 63;
    const int wid  = threadIdx.x >> 6;
    if (lane == 0) {
#pragma unroll
        for (int k = 0; k < NACC; ++k) sh[wid][k] = a[k];
    }
    __syncthreads();

    const unsigned tid = threadIdx.x;
    if (tid < NACC) {
        double s = 0.0;
#pragma unroll
        for (int w = 0; w < NWAVES; ++w) s += (double)sh[w][tid];
        __hip_atomic_store(&part[blockIdx.x * NACC + (int)tid], s,
                           __ATOMIC_RELAXED, __HIP_MEMORY_SCOPE_AGENT);
    }
    __syncthreads();

    __shared__ bool amLast;
    if (tid == 0) {
        __threadfence();
        unsigned prev = atomicAdd(counter, 1u);
        amLast = (prev == gridDim.x - 1);
    }
    __syncthreads();

    if (amLast) {
        __threadfence();
        __shared__ double red[8][NACC];
        __shared__ double tot[NACC];
        const int k = (int)tid % NACC;
        const int g = (int)tid / NACC;
        if (tid < 8 * NACC) {
            double s = 0.0;
#pragma unroll
            for (int b = 0; b < RBLOCKS / 8; ++b) {
                const int blk = g + b * 8;
                s += __hip_atomic_load(&part[blk * NACC + k],
                                       __ATOMIC_RELAXED, __HIP_MEMORY_SCOPE_AGENT);
            }
            red[g][k] = s;
        }
        __syncthreads();
        if (tid < NACC) {
            double s = 0.0;
#pragma unroll
            for (int g2 = 0; g2 < 8; ++g2) s += red[g2][tid];
            tot[tid] = s;
        }
        __syncthreads();
        if (tid == 0) {
            solve_and_update(tot, ws, pose_in, it, out, write_out);
            atomicExch(counter, 0u);
        }
    }
}

// ---------------------------------------------------------------------------
// Slice-strided mapping (R9-proven): thread handles pixels {tid0 + s*STRIDE},
// consecutive lanes own consecutive pixels -> gather instructions have ~12B
// lane stride (~12 lines/inst instead of 48-64). This round: 512 threads
// (2 waves/SIMD) to double outstanding misses in both the cold-HBM and
// steady-L3 regimes (R1/R3 anti-scaling was an artifact of the old mapping).
__global__ __launch_bounds__(RTPB, 1) void icp_fused(
    const float* __restrict__ pose_in,
    const float* __restrict__ vert0, const float* __restrict__ vert1,
    const float* __restrict__ norm0, const float* __restrict__ norm1,
    const float* __restrict__ Kmat, double* __restrict__ ws,
    float* __restrict__ out, int it, int write_out)
{
    // ---- pose: iter0 from input, else from ws (written by prior dispatch) ----
    float R00, R01, R02, t0, R10, R11, R12, t1, R20, R21, R22, t2;
    if (it == 0) {
        R00 = pose_in[0];  R01 = pose_in[1];  R02 = pose_in[2];  t0 = pose_in[3];
        R10 = pose_in[4];  R11 = pose_in[5];  R12 = pose_in[6];  t1 = pose_in[7];
        R20 = pose_in[8];  R21 = pose_in[9];  R22 = pose_in[10]; t2 = pose_in[11];
    } else {
        const double* pose = ws;
        R00 = (float)pose[0];  R01 = (float)pose[1];  R02 = (float)pose[2];  t0 = (float)pose[3];
        R10 = (float)pose[4];  R11 = (float)pose[5];  R12 = (float)pose[6];  t1 = (float)pose[7];
        R20 = (float)pose[8];  R21 = (float)pose[9];  R22 = (float)pose[10]; t2 = (float)pose[11];
    }
    const float fx = Kmat[0], cx = Kmat[2], fy = Kmat[4], cy = Kmat[5];

    float a[NACC];
#pragma unroll
    for (int k = 0; k < NACC; ++k) a[k] = 0.0f;

    // XCD-chunked swizzle (bijective: 256 = 8 XCDs x 32).
    const int sbid = (blockIdx.x & 7) * 32 + (blockIdx.x >> 3);
    const int tid0 = sbid * RTPB + (int)threadIdx.x;

    // current-group stream regs (GSLOTS pixel-slots x {vx,vy,vz,nx,ny,nz})
    float cs[GSLOTS][6];
#pragma unroll
    for (int j = 0; j < GSLOTS; ++j) {
        const int pix = tid0 + j * STRIDE;
        const int b = pix * 3;
        cs[j][0] = vert0[b + 0]; cs[j][1] = vert0[b + 1]; cs[j][2] = vert0[b + 2];
        cs[j][3] = norm0[b + 0]; cs[j][4] = norm0[b + 1]; cs[j][5] = norm0[b + 2];
    }

#pragma unroll
    for (int i = 0; i < NGROUPS; ++i) {
        // ---- phase A: project GSLOTS slots, compute gather bases ----
        float px[GSLOTS], py[GSLOTS], pz[GSLOTS];
        float nrx[GSLOTS], nry[GSLOTS], nrz[GSLOTS];
        bool inview[GSLOTS];
        int wb[GSLOTS];
#pragma unroll
        for (int j = 0; j < GSLOTS; ++j) {
            const float vx = cs[j][0], vy = cs[j][1], vz = cs[j][2];
            const float nx = cs[j][3], ny = cs[j][4], nz = cs[j][5];
            px[j] = R00 * vx + R01 * vy + R02 * vz + t0;
            py[j] = R10 * vx + R11 * vy + R12 * vz + t1;
            pz[j] = R20 * vx + R21 * vy + R22 * vz + t2;
            nrx[j] = R00 * nx + R01 * ny + R02 * nz;
            nry[j] = R10 * nx + R11 * ny + R12 * nz;
            nrz[j] = R20 * nx + R21 * ny + R22 * nz;
            const float u = px[j] / pz[j] * fx + cx;
            const float v = py[j] / pz[j] * fy + cy;
            inview[j] = (u > 0.0f) && (u < (float)(W_IMG - 1)) &&
                        (v > 0.0f) && (v < (float)(H_IMG - 1));
            const float uf = fminf(fmaxf(rintf(u), 0.0f), (float)(W_IMG - 1));
            const float vf = fminf(fmaxf(rintf(v), 0.0f), (float)(H_IMG - 1));
            wb[j] = ((int)vf * W_IMG + (int)uf) * 3;
        }

        // ---- phase B: scalar gathers (lane-consecutive addresses) ----
        float r1x[GSLOTS], r1y[GSLOTS], r1z[GSLOTS];
        float m1x[GSLOTS], m1y[GSLOTS], m1z[GSLOTS];
#pragma unroll
        for (int j = 0; j < GSLOTS; ++j) {
            r1x[j] = vert1[wb[j]]; r1y[j] = vert1[wb[j] + 1]; r1z[j] = vert1[wb[j] + 2];
            m1x[j] = norm1[wb[j]]; m1y[j] = norm1[wb[j] + 1]; m1z[j] = norm1[wb[j] + 2];
        }

        // ---- prefetch next group's streams (overlaps gather latency) ----
        float ns[GSLOTS][6];
        if (i + 1 < NGROUPS) {
#pragma unroll
            for (int j = 0; j < GSLOTS; ++j) {
                const int pix = tid0 + ((i + 1) * GSLOTS + j) * STRIDE;
                const int b = pix * 3;
                ns[j][0] = vert0[b + 0]; ns[j][1] = vert0[b + 1]; ns[j][2] = vert0[b + 2];
                ns[j][3] = norm0[b + 0]; ns[j][4] = norm0[b + 1]; ns[j][5] = norm0[b + 2];
            }
        }

        // ---- phase C: consume, accumulate ----
#pragma unroll
        for (int j = 0; j < GSLOTS; ++j) {
            const float dx = px[j] - r1x[j], dy = py[j] - r1y[j], dz = pz[j] - r1z[j];
            const bool mask0 = cs[j][2] > 0.0f;
            const bool mask1 = r1z[j] > 0.0f;
            const bool normal_ok =
                (nrx[j] * m1x[j] + nry[j] * m1y[j] + nrz[j] * m1z[j]) > NORM_THR;
            const float d2 = dx * dx + dy * dy + dz * dz;
            const bool occ = (!inview[j]) || (d2 > DIST_THR2);
            const bool valid = (!occ) && mask0 && mask1 && normal_ok;

            if (valid) {
                const float res = m1x[j] * dx + m1y[j] * dy + m1z[j] * dz;
                float J[6];
                J[0] = py[j] * m1z[j] - pz[j] * m1y[j];
                J[1] = pz[j] * m1x[j] - px[j] * m1z[j];
                J[2] = px[j] * m1y[j] - py[j] * m1x[j];
                J[3] = m1x[j]; J[4] = m1y[j]; J[5] = m1z[j];
                int k = 0;
#pragma unroll
                for (int ii = 0; ii < 6; ++ii)
#pragma unroll
                    for (int jj = ii; jj < 6; ++jj) a[k++] += J[ii] * J[jj];
#pragma unroll
                for (int ii = 0; ii < 6; ++ii) a[21 + ii] += J[ii] * res;
                a[27] += 1.0f;
            }
        }

        if (i + 1 < NGROUPS) {
#pragma unroll
            for (int j = 0; j < GSLOTS; ++j)
#pragma unroll
                for (int c = 0; c < 6; ++c) cs[j][c] = ns[j][c];
        }
    }

    reduce_and_finish(a, ws, pose_in, it, out, write_out);
}

// ---------------------------------------------------------------------------
extern "C" void kernel_launch(void* const* d_in, const int* in_sizes, int n_in,
                              void* d_out, int out_size, void* d_ws, size_t ws_size,
                              hipStream_t stream) {
    const float* pose10 = (const float*)d_in[0];
    const float* vert0  = (const float*)d_in[1];
    const float* vert1  = (const float*)d_in[2];
    const float* norm0  = (const float*)d_in[3];
    const float* norm1  = (const float*)d_in[4];
    const float* Kmat   = (const float*)d_in[5];
    float* out = (float*)d_out;
    double* ws = (double*)d_ws;

    icp_init0<<<1, 64, 0, stream>>>(ws);
    for (int it = 0; it < 3; ++it) {
        icp_fused<<<RBLOCKS, RTPB, 0, stream>>>(pose10, vert0, vert1, norm0, norm1,
                                                Kmat, ws, out, it, it == 2 ? 1 : 0);
    }
}